// Round 6
// baseline (23271.275 us; speedup 1.0000x reference)
//
#include <hip/hip_runtime.h>

// Problem constants
#define B_ 64
#define S_ 64
#define T_ 64
#define V_ 32000
#define D_ 512
#define H_ 1024
#define L_ 256
#define NBLK 256

typedef _Float16 f16;
typedef __attribute__((ext_vector_type(4))) _Float16 f16x4;
typedef __attribute__((ext_vector_type(8))) _Float16 f16x8;
typedef __attribute__((ext_vector_type(16))) float f32x16;

#define INV2048 (1.0f / 2048.0f)

// ---------------------------------------------------------------------------
// Grid barrier (sense-free monotonic generation). All 256 blocks co-resident:
// LDS 36KB (<64KB) and launch_bounds(256,2) give >=2 blocks/CU capacity, so
// the dispatcher can never strand a block. cnt/gen zeroed per kernel_launch.
// ---------------------------------------------------------------------------
__device__ __forceinline__ void gbar(unsigned* cnt, unsigned* gen, unsigned tgt) {
  __syncthreads();
  if (threadIdx.x == 0) {
    __threadfence();
    unsigned old = __hip_atomic_fetch_add(cnt, 1u, __ATOMIC_ACQ_REL, __HIP_MEMORY_SCOPE_AGENT);
    if (old == NBLK - 1) {
      __hip_atomic_store(cnt, 0u, __ATOMIC_RELAXED, __HIP_MEMORY_SCOPE_AGENT);
      __hip_atomic_fetch_add(gen, 1u, __ATOMIC_RELEASE, __HIP_MEMORY_SCOPE_AGENT);
    } else {
      while (__hip_atomic_load(gen, __ATOMIC_ACQUIRE, __HIP_MEMORY_SCOPE_AGENT) < tgt)
        __builtin_amdgcn_s_sleep(2);
    }
  }
  __syncthreads();
  __threadfence();
}

// ---------------------------------------------------------------------------
// f16 hi/lo frag write for h values (A-operand layout, m=b, k=j).
// ---------------------------------------------------------------------------
__device__ __forceinline__ void write_frag(f16* __restrict__ Aohi, f16* __restrict__ Aolo,
                                           int b, int j, float hv) {
  const f16 hi = (f16)hv;
  const f16 lo = (f16)((hv - (float)hi) * 2048.0f);
  const long long fo =
      (((long long)(b >> 5) * 64 + (j >> 4)) * 64 + ((b & 31) + 32 * ((j >> 3) & 1))) * 8 + (j & 7);
  Aohi[fo] = hi;
  Aolo[fo] = lo;
}

// ---------------------------------------------------------------------------
// Pack fp32 weights [N][K] into MFMA B-frag-major f16 hi/lo.
// ---------------------------------------------------------------------------
template <int K>
__global__ __launch_bounds__(256) void k_pack_wf(
    const float* __restrict__ W, f16* __restrict__ Bhi, f16* __restrict__ Blo)
{
  const int n = blockIdx.x;
  const int k = threadIdx.x * 4;
  if (k >= K) return;
  float4 w = *reinterpret_cast<const float4*>(W + (long long)n * K + k);
  float wv[4] = {w.x, w.y, w.z, w.w};
  f16x4 hi, lo;
#pragma unroll
  for (int i = 0; i < 4; ++i) {
    const f16 h = (f16)wv[i];
    hi[i] = h;
    lo[i] = (f16)((wv[i] - (float)h) * 2048.0f);
  }
  const int nt = n >> 5;
  const int lane = (n & 31) + 32 * ((k >> 3) & 1);
  const int ks = k >> 4;
  const long long off = (((long long)nt * (K / 16) + ks) * 64 + lane) * 8 + (k & 7);
  *reinterpret_cast<f16x4*>(Bhi + off) = hi;
  *reinterpret_cast<f16x4*>(Blo + off) = lo;
}

// ---------------------------------------------------------------------------
// Pack encoder token embeddings into A-frags (m = s*64+b, K = 512).
// ---------------------------------------------------------------------------
__global__ __launch_bounds__(128) void k_pack_xe(
    const int* __restrict__ x, const float* __restrict__ E,
    f16* __restrict__ XAhi, f16* __restrict__ XAlo)
{
  const int m = blockIdx.x;
  const int s = m >> 6, b = m & 63;
  const int k = threadIdx.x * 4;
  const long long tok = x[b * S_ + s];
  float4 w = *reinterpret_cast<const float4*>(E + tok * D_ + k);
  float wv[4] = {w.x, w.y, w.z, w.w};
  f16x4 hi, lo;
#pragma unroll
  for (int i = 0; i < 4; ++i) {
    const f16 h = (f16)wv[i];
    hi[i] = h;
    lo[i] = (f16)((wv[i] - (float)h) * 2048.0f);
  }
  const int mt = m >> 5;
  const int lane = (m & 31) + 32 * ((k >> 3) & 1);
  const int ks = k >> 4;
  const long long off = (((long long)mt * 32 + ks) * 64 + lane) * 8 + (k & 7);
  *reinterpret_cast<f16x4*>(XAhi + off) = hi;
  *reinterpret_cast<f16x4*>(XAlo + off) = lo;
}

// ---------------------------------------------------------------------------
// Encoder input-gates GEMM (proven round-5 kernel).
// ---------------------------------------------------------------------------
__global__ __launch_bounds__(256) void k_gates_mfma(
    const f16* __restrict__ XAhi, const f16* __restrict__ XAlo,
    const f16* __restrict__ Bhi, const f16* __restrict__ Blo,
    const float* __restrict__ b_ih, float* __restrict__ Gi)
{
  __shared__ float cand[4][64][33];
  const int tid = threadIdx.x;
  const int lane = tid & 63;
  const int wv = __builtin_amdgcn_readfirstlane(tid >> 6);
  const int s = blockIdx.x / 24;
  const int ng = blockIdx.x % 24;
  const int nt = ng * 4 + wv;

  f32x16 aM0, aM1, aLa0, aLa1, aLb0, aLb1;
#pragma unroll
  for (int i = 0; i < 16; ++i) {
    aM0[i] = 0.f; aM1[i] = 0.f; aLa0[i] = 0.f; aLa1[i] = 0.f; aLb0[i] = 0.f; aLb1[i] = 0.f;
  }

  const f16x8* pB_h = reinterpret_cast<const f16x8*>(Bhi) + ((long long)nt * 32) * 64 + lane;
  const f16x8* pB_l = reinterpret_cast<const f16x8*>(Blo) + ((long long)nt * 32) * 64 + lane;
  const f16x8* pA_h = reinterpret_cast<const f16x8*>(XAhi) + ((long long)s * 64) * 64 + lane;
  const f16x8* pA_l = reinterpret_cast<const f16x8*>(XAlo) + ((long long)s * 64) * 64 + lane;

#pragma unroll 4
  for (int ks = 0; ks < 32; ++ks) {
    const int o = ks * 64;
    f16x8 bh = pB_h[o];
    f16x8 bl = pB_l[o];
    f16x8 a0 = pA_h[o];
    f16x8 a1 = pA_h[o + 32 * 64];
    f16x8 l0 = pA_l[o];
    f16x8 l1 = pA_l[o + 32 * 64];
    aM0 = __builtin_amdgcn_mfma_f32_32x32x16_f16(a0, bh, aM0, 0, 0, 0);
    aM1 = __builtin_amdgcn_mfma_f32_32x32x16_f16(a1, bh, aM1, 0, 0, 0);
    aLa0 = __builtin_amdgcn_mfma_f32_32x32x16_f16(a0, bl, aLa0, 0, 0, 0);
    aLa1 = __builtin_amdgcn_mfma_f32_32x32x16_f16(a1, bl, aLa1, 0, 0, 0);
    aLb0 = __builtin_amdgcn_mfma_f32_32x32x16_f16(l0, bh, aLb0, 0, 0, 0);
    aLb1 = __builtin_amdgcn_mfma_f32_32x32x16_f16(l1, bh, aLb1, 0, 0, 0);
  }

  {
    const int l = lane & 31;
    const int rbase = 4 * (lane >> 5);
#pragma unroll
    for (int reg = 0; reg < 16; ++reg) {
      const int row = (reg & 3) + 8 * (reg >> 2) + rbase;
      cand[wv][row][l] = aM0[reg] + (aLa0[reg] + aLb0[reg]) * INV2048;
      cand[wv][row + 32][l] = aM1[reg] + (aLa1[reg] + aLb1[reg]) * INV2048;
    }
  }
  __syncthreads();
  const int bn0 = ng * 128;
#pragma unroll
  for (int i = 0; i < 8; ++i) {
    const int idx = i * 256 + tid;
    const int b4 = (idx & 15) * 4;
    const int nl = idx >> 4;
    const float bi = b_ih[bn0 + nl];
    float4 o;
    o.x = cand[nl >> 5][b4 + 0][nl & 31] + bi;
    o.y = cand[nl >> 5][b4 + 1][nl & 31] + bi;
    o.z = cand[nl >> 5][b4 + 2][nl & 31] + bi;
    o.w = cand[nl >> 5][b4 + 3][nl & 31] + bi;
    *reinterpret_cast<float4*>(&Gi[((long long)s * (3 * H_) + bn0 + nl) * 64 + b4]) = o;
  }
}

// ---------------------------------------------------------------------------
// MFMA pre-activation phase helper: one block computes one nt (32 n-cols x
// 64 b), 4 waves = K-slices, LDS reduce, writes outp[32][64].
// NITER = k-iters per wave; AMT = A mt-stride in f16x8 units.
// ---------------------------------------------------------------------------
template <int NITER, int AMT>
__device__ __forceinline__ void mm_phase(
    const f16* __restrict__ Ah, const f16* __restrict__ Al,
    const f16* __restrict__ Bh, const f16* __restrict__ Bl,
    int nt, int wv, int lane, int tid,
    float (*cand)[64][33], float* __restrict__ outp)
{
  f32x16 aM0, aM1, aLa0, aLa1, aLb0, aLb1;
#pragma unroll
  for (int i = 0; i < 16; ++i) {
    aM0[i] = 0.f; aM1[i] = 0.f; aLa0[i] = 0.f; aLa1[i] = 0.f; aLb0[i] = 0.f; aLb1[i] = 0.f;
  }
  const f16x8* pBh = reinterpret_cast<const f16x8*>(Bh) + ((long long)nt * (4 * NITER) + wv * NITER) * 64 + lane;
  const f16x8* pBl = reinterpret_cast<const f16x8*>(Bl) + ((long long)nt * (4 * NITER) + wv * NITER) * 64 + lane;
  const f16x8* pAh = reinterpret_cast<const f16x8*>(Ah) + (long long)(wv * NITER) * 64 + lane;
  const f16x8* pAl = reinterpret_cast<const f16x8*>(Al) + (long long)(wv * NITER) * 64 + lane;
#pragma unroll 4
  for (int q = 0; q < NITER; ++q) {
    const int o = q * 64;
    f16x8 bh = pBh[o];
    f16x8 bl = pBl[o];
    f16x8 a0 = pAh[o];
    f16x8 a1 = pAh[o + AMT];
    f16x8 l0 = pAl[o];
    f16x8 l1 = pAl[o + AMT];
    aM0 = __builtin_amdgcn_mfma_f32_32x32x16_f16(a0, bh, aM0, 0, 0, 0);
    aM1 = __builtin_amdgcn_mfma_f32_32x32x16_f16(a1, bh, aM1, 0, 0, 0);
    aLa0 = __builtin_amdgcn_mfma_f32_32x32x16_f16(a0, bl, aLa0, 0, 0, 0);
    aLa1 = __builtin_amdgcn_mfma_f32_32x32x16_f16(a1, bl, aLa1, 0, 0, 0);
    aLb0 = __builtin_amdgcn_mfma_f32_32x32x16_f16(l0, bh, aLb0, 0, 0, 0);
    aLb1 = __builtin_amdgcn_mfma_f32_32x32x16_f16(l1, bh, aLb1, 0, 0, 0);
  }
  {
    const int l = lane & 31;
    const int rbase = 4 * (lane >> 5);
#pragma unroll
    for (int reg = 0; reg < 16; ++reg) {
      const int row = (reg & 3) + 8 * (reg >> 2) + rbase;
      cand[wv][row][l] = aM0[reg] + (aLa0[reg] + aLb0[reg]) * INV2048;
      cand[wv][row + 32][l] = aM1[reg] + (aLa1[reg] + aLb1[reg]) * INV2048;
    }
  }
  __syncthreads();
#pragma unroll
  for (int i = 0; i < 8; ++i) {
    const int idx = i * 256 + tid;
    const int b = idx & 63;
    const int l2 = idx >> 6;
    const float v = cand[0][b][l2] + cand[1][b][l2] + cand[2][b][l2] + cand[3][b][l2];
    outp[(long long)l2 * 64 + b] = v;
  }
}

// ---------------------------------------------------------------------------
// Persistent encoder: 64 steps x { P1 hh-MFMA (blocks 0..95), B, P2 apply, B }.
// ---------------------------------------------------------------------------
__global__ __launch_bounds__(256, 2) void k_enc_persist(
    const f16* __restrict__ WHEhi, const f16* __restrict__ WHElo,
    const float* __restrict__ Gi, const float* __restrict__ b_hh,
    float* __restrict__ hT, float* __restrict__ preH,
    f16* __restrict__ frAhi, f16* __restrict__ frAlo,
    unsigned* cnt, unsigned* gen)
{
  __shared__ float cand[4][64][33];
  const int tid = threadIdx.x;
  const int lane = tid & 63;
  const int wv = __builtin_amdgcn_readfirstlane(tid >> 6);
  const int gtid = blockIdx.x * 256 + tid;
  const int jc = gtid >> 6;
  const int b = gtid & 63;
  unsigned tgt = 0;

  for (int t = 0; t < S_; ++t) {
    if (blockIdx.x < 96)
      mm_phase<16, 4096>(frAhi, frAlo, WHEhi, WHElo, blockIdx.x, wv, lane, tid,
                         cand, preH + (long long)blockIdx.x * 2048);
    gbar(cnt, gen, ++tgt);
    {
      const float* Gt = Gi + (long long)t * 3 * H_ * 64;
      const float gr = preH[(long long)jc * 64 + b] + Gt[(long long)jc * 64 + b] + b_hh[jc];
      const float gz = preH[(long long)(H_ + jc) * 64 + b] + Gt[(long long)(H_ + jc) * 64 + b] + b_hh[H_ + jc];
      const float gin = Gt[(long long)(2 * H_ + jc) * 64 + b];
      const float ghn = preH[(long long)(2 * H_ + jc) * 64 + b] + b_hh[2 * H_ + jc];
      const float r = 1.f / (1.f + expf(-gr));
      const float z = 1.f / (1.f + expf(-gz));
      const float n = tanhf(fmaf(r, ghn, gin));
      const float hp = hT[(long long)jc * 64 + b];
      const float hv = (1.f - z) * n + z * hp;
      hT[(long long)jc * 64 + b] = hv;
      write_frag(frAhi, frAlo, b, jc, hv);
    }
    gbar(cnt, gen, ++tgt);
  }
}

// ---------------------------------------------------------------------------
// Persistent decoder: 64 steps x 4 phases:
// P1 hh (blocks 0..95) + ih from XA frags (96..191); P2 apply; P3 logits
// (blocks 0..249, f16x3 + NT stores + partial argmax); P4 fold+gather XA.
// ---------------------------------------------------------------------------
__global__ __launch_bounds__(256, 2) void k_dec_persist(
    const float* __restrict__ E,
    const f16* __restrict__ WHDhi, const f16* __restrict__ WHDlo,
    const f16* __restrict__ WIDhi, const f16* __restrict__ WIDlo,
    const f16* __restrict__ WOhi, const f16* __restrict__ WOlo,
    const float* __restrict__ b_ih, const float* __restrict__ b_hh,
    const float* __restrict__ b_out, float* __restrict__ out,
    unsigned long long* __restrict__ bestPart,
    float* __restrict__ preH, float* __restrict__ preI,
    float* __restrict__ hT, f16* __restrict__ frAhi, f16* __restrict__ frAlo,
    f16* __restrict__ XAhi, f16* __restrict__ XAlo,
    unsigned* cnt, unsigned* gen)
{
  __shared__ float cand[4][64][33];
  __shared__ unsigned long long wbest[4][64];
  const int tid = threadIdx.x;
  const int lane = tid & 63;
  const int wv = __builtin_amdgcn_readfirstlane(tid >> 6);
  const int gtid = blockIdx.x * 256 + tid;
  const int jc = gtid >> 6;
  const int b = gtid & 63;
  unsigned tgt = 0;

  for (int t = 0; t < T_; ++t) {
    // ---- P1: pre-activations ----
    if (blockIdx.x < 96)
      mm_phase<16, 4096>(frAhi, frAlo, WHDhi, WHDlo, blockIdx.x, wv, lane, tid,
                         cand, preH + (long long)blockIdx.x * 2048);
    else if (blockIdx.x < 192)
      mm_phase<8, 2048>(XAhi, XAlo, WIDhi, WIDlo, blockIdx.x - 96, wv, lane, tid,
                        cand, preI + (long long)(blockIdx.x - 96) * 2048);
    gbar(cnt, gen, ++tgt);

    // ---- P2: gate apply ----
    {
      const float gr = preI[(long long)jc * 64 + b] + preH[(long long)jc * 64 + b] + b_ih[jc] + b_hh[jc];
      const float gz = preI[(long long)(H_ + jc) * 64 + b] + preH[(long long)(H_ + jc) * 64 + b] +
                       b_ih[H_ + jc] + b_hh[H_ + jc];
      const float gin = preI[(long long)(2 * H_ + jc) * 64 + b] + b_ih[2 * H_ + jc];
      const float ghn = preH[(long long)(2 * H_ + jc) * 64 + b] + b_hh[2 * H_ + jc];
      const float r = 1.f / (1.f + expf(-gr));
      const float z = 1.f / (1.f + expf(-gz));
      const float n = tanhf(fmaf(r, ghn, gin));
      const float hp = hT[(long long)jc * 64 + b];
      const float hv = (1.f - z) * n + z * hp;
      hT[(long long)jc * 64 + b] = hv;
      write_frag(frAhi, frAlo, b, jc, hv);
    }
    gbar(cnt, gen, ++tgt);

    // ---- P3: logits f16x3 + partial argmax ----
    if (blockIdx.x < 250) {
      const int nt = blockIdx.x * 4 + wv;
      f32x16 accM0, accM1, accL0, accL1;
#pragma unroll
      for (int i = 0; i < 16; ++i) { accM0[i] = 0.f; accM1[i] = 0.f; accL0[i] = 0.f; accL1[i] = 0.f; }

      const f16x8* pAh0 = reinterpret_cast<const f16x8*>(frAhi) + lane;
      const f16x8* pAh1 = reinterpret_cast<const f16x8*>(frAhi) + 4096 + lane;
      const f16x8* pAl0 = reinterpret_cast<const f16x8*>(frAlo) + lane;
      const f16x8* pAl1 = reinterpret_cast<const f16x8*>(frAlo) + 4096 + lane;
      const f16x8* pBh = reinterpret_cast<const f16x8*>(WOhi) + (long long)nt * 4096 + lane;
      const f16x8* pBl = reinterpret_cast<const f16x8*>(WOlo) + (long long)nt * 4096 + lane;

#pragma unroll 4
      for (int ksi = 0; ksi < 64; ++ksi) {
        const int o = ksi * 64;
        f16x8 bh = pBh[o];
        f16x8 bl = pBl[o];
        f16x8 ah0 = pAh0[o];
        f16x8 ah1 = pAh1[o];
        f16x8 al0 = pAl0[o];
        f16x8 al1 = pAl1[o];
        accM0 = __builtin_amdgcn_mfma_f32_32x32x16_f16(ah0, bh, accM0, 0, 0, 0);
        accM1 = __builtin_amdgcn_mfma_f32_32x32x16_f16(ah1, bh, accM1, 0, 0, 0);
        accL0 = __builtin_amdgcn_mfma_f32_32x32x16_f16(ah0, bl, accL0, 0, 0, 0);
        accL1 = __builtin_amdgcn_mfma_f32_32x32x16_f16(ah1, bl, accL1, 0, 0, 0);
        accL0 = __builtin_amdgcn_mfma_f32_32x32x16_f16(al0, bh, accL0, 0, 0, 0);
        accL1 = __builtin_amdgcn_mfma_f32_32x32x16_f16(al1, bh, accL1, 0, 0, 0);
      }

      const int nn = nt * 32 + (lane & 31);
      const float bo = b_out[nn];
      const int rbase = 4 * (lane >> 5);
#pragma unroll
      for (int reg = 0; reg < 16; ++reg) {
        const int row0 = (reg & 3) + 8 * (reg >> 2) + rbase;
        const float v0 = accM0[reg] + accL0[reg] * INV2048 + bo;
        __builtin_nontemporal_store(v0, &out[(long long)row0 * (T_ * (long long)V_) + (long long)t * V_ + nn]);
        cand[wv][row0][lane & 31] = v0;
        const int row1 = row0 + 32;
        const float v1 = accM1[reg] + accL1[reg] * INV2048 + bo;
        __builtin_nontemporal_store(v1, &out[(long long)row1 * (T_ * (long long)V_) + (long long)t * V_ + nn]);
        cand[wv][row1][lane & 31] = v1;
      }
      __syncthreads();
      {
        const int w = tid >> 6, r = tid & 63;
        const int nb = (blockIdx.x * 4 + w) * 32;
        unsigned long long kk = 0ull;
#pragma unroll
        for (int l0 = 0; l0 < 32; ++l0) {
          const int l = (l0 + r) & 31;
          const float v = cand[w][r][l];
          unsigned u = __float_as_uint(v);
          u = (u & 0x80000000u) ? ~u : (u | 0x80000000u);
          const unsigned long long key = ((unsigned long long)u << 32) |
              (unsigned long long)(0xFFFFFFFFu - (unsigned)(nb + l));
          if (key > kk) kk = key;
        }
        wbest[w][r] = kk;
      }
      __syncthreads();
      if (tid < 64) {
        unsigned long long kk = wbest[0][tid];
#pragma unroll
        for (int w = 1; w < 4; ++w) { const unsigned long long q = wbest[w][tid]; if (q > kk) kk = q; }
        bestPart[(long long)tid * 256 + blockIdx.x] = kk;
      }
    }
    gbar(cnt, gen, ++tgt);

    // ---- P4: fold argmax + gather next-token embedding into XA frags ----
    if (blockIdx.x < 16) {
      const int r = blockIdx.x * 4 + wv;
      unsigned long long kk = 0ull;
#pragma unroll
      for (int i = 0; i < 4; ++i) {
        const unsigned long long q = bestPart[(long long)r * 256 + lane + i * 64];
        if (q > kk) kk = q;
      }
#pragma unroll
      for (int m = 1; m < 64; m <<= 1) {
        const unsigned long long q = __shfl_xor(kk, m, 64);
        if (q > kk) kk = q;
      }
      const int tok = (int)(0xFFFFFFFFu - (unsigned)(kk & 0xFFFFFFFFull));
      const float* ep = E + (long long)tok * D_ + lane * 8;
      float4 v0 = *reinterpret_cast<const float4*>(ep);
      float4 v1 = *reinterpret_cast<const float4*>(ep + 4);
      float vv[8] = {v0.x, v0.y, v0.z, v0.w, v1.x, v1.y, v1.z, v1.w};
      f16x8 hi, lo;
#pragma unroll
      for (int e = 0; e < 8; ++e) {
        const f16 h = (f16)vv[e];
        hi[e] = h;
        lo[e] = (f16)((vv[e] - (float)h) * 2048.0f);
      }
      const long long unit = (((long long)(r >> 5) * 32 + (lane >> 1)) * 64 + ((r & 31) + 32 * (lane & 1)));
      *reinterpret_cast<f16x8*>(XAhi + unit * 8) = hi;
      *reinterpret_cast<f16x8*>(XAlo + unit * 8) = lo;
    }
    gbar(cnt, gen, ++tgt);
  }
}

// ---------------------------------------------------------------------------
// mu / logvar / z from hT. grid = 64 x 256; wave = latent col l, lane = b.
// ---------------------------------------------------------------------------
__global__ __launch_bounds__(256) void k_mu_lv_z(
    const float* __restrict__ hT, const float* __restrict__ W_mu, const float* __restrict__ b_mu,
    const float* __restrict__ W_lv, const float* __restrict__ b_lv,
    const float* __restrict__ eps, float* __restrict__ out_mu, float* __restrict__ out_lv,
    float* __restrict__ zT)
{
  const int lane = threadIdx.x & 63;
  const int wv = __builtin_amdgcn_readfirstlane(threadIdx.x >> 6);
  const int l = blockIdx.x * 4 + wv;
  const float* wm = W_mu + (long long)l * H_;
  const float* wl = W_lv + (long long)l * H_;
  float am = 0.f, av = 0.f;
#pragma unroll 8
  for (int k = 0; k < H_; ++k) {
    const float h = hT[k * 64 + lane];
    am = fmaf(wm[k], h, am);
    av = fmaf(wl[k], h, av);
  }
  const float mu = am + b_mu[l];
  const float lv = av + b_lv[l];
  out_mu[lane * L_ + l] = mu;
  out_lv[lane * L_ + l] = lv;
  zT[l * 64 + lane] = fmaf(eps[lane * L_ + l], expf(0.5f * lv), mu);
}

// ---------------------------------------------------------------------------
// h_dec0 = z @ W_proj.T + b_proj. Writes hT0 + A-frags. grid = 256 x 256.
// ---------------------------------------------------------------------------
__global__ __launch_bounds__(256) void k_proj(
    const float* __restrict__ zT, const float* __restrict__ W_proj,
    const float* __restrict__ b_proj, float* __restrict__ hT0,
    f16* __restrict__ Aohi, f16* __restrict__ Aolo)
{
  const int lane = threadIdx.x & 63;
  const int wv = __builtin_amdgcn_readfirstlane(threadIdx.x >> 6);
  const int j = blockIdx.x * 4 + wv;
  const float* wr = W_proj + (long long)j * L_;
  float acc = 0.f;
#pragma unroll 8
  for (int k = 0; k < L_; ++k) acc = fmaf(wr[k], zT[k * 64 + lane], acc);
  const float hv = acc + b_proj[j];
  hT0[(long long)j * 64 + lane] = hv;
  write_frag(Aohi, Aolo, lane, j, hv);
}

// ---------------------------------------------------------------------------
extern "C" void kernel_launch(void* const* d_in, const int* in_sizes, int n_in,
                              void* d_out, int out_size, void* d_ws, size_t ws_size,
                              hipStream_t stream) {
  (void)in_sizes; (void)n_in; (void)out_size;
  const int*   x        = (const int*)d_in[0];
  const float* eps      = (const float*)d_in[1];
  const float* E        = (const float*)d_in[2];
  const float* W_ih_enc = (const float*)d_in[3];
  const float* W_hh_enc = (const float*)d_in[4];
  const float* b_ih_enc = (const float*)d_in[5];
  const float* b_hh_enc = (const float*)d_in[6];
  const float* W_mu     = (const float*)d_in[7];
  const float* b_mu     = (const float*)d_in[8];
  const float* W_lv     = (const float*)d_in[9];
  const float* b_lv     = (const float*)d_in[10];
  const float* W_proj   = (const float*)d_in[11];
  const float* b_proj   = (const float*)d_in[12];
  const float* W_ih_dec = (const float*)d_in[13];
  const float* W_hh_dec = (const float*)d_in[14];
  const float* b_ih_dec = (const float*)d_in[15];
  const float* b_hh_dec = (const float*)d_in[16];
  const float* W_out    = (const float*)d_in[17];
  const float* b_out    = (const float*)d_in[18];

  float* out = (float*)d_out;
  const long long OFF_MU = (long long)B_ * T_ * V_;
  const long long OFF_LV = OFF_MU + (long long)B_ * L_;

  // Workspace layout (float offsets)
  float* ws = (float*)d_ws;
  float* hA   = ws + 0;               // enc hT (in-place)       65536
  float* dA   = ws + 65536;           // dec hT (in-place)       65536
  float* zT   = ws + 131072;          //                         16384
  unsigned long long* bestPart = (unsigned long long*)(ws + 147456);  // 32768 fl
  float* preH = ws + 180224;          // [3072][64]              196608
  float* preI = ws + 376832;          // [3072][64]              196608
  f16* frAhi  = (f16*)(ws + 573440);  // h A-frags               32768 fl
  f16* frAlo  = (f16*)(ws + 606208);
  f16* WHEhi  = (f16*)(ws + 638976);  // [96][64][64][8]         1572864 fl
  f16* WHElo  = (f16*)(ws + 2211840);
  f16* WHDhi  = (f16*)(ws + 3784704);
  f16* WHDlo  = (f16*)(ws + 5357568);
  f16* WIEhi  = (f16*)(ws + 6930432); // [96][32][64][8]         786432 fl
  f16* WIElo  = (f16*)(ws + 7716864);
  f16* WIDhi  = (f16*)(ws + 8503296);
  f16* WIDlo  = (f16*)(ws + 9289728);
  unsigned* bar = (unsigned*)(ws + 10076160);  // 256 fl: enc cnt@0 gen@32, dec cnt@64 gen@96
  f16* XAdhi  = (f16*)(ws + 10076416); // dec token frags [2][32][64][8]  16384 fl
  f16* XAdlo  = (f16*)(ws + 10092800);
  // overlay: {XAenc + Gi} (encoder phase) then {WO frags} (decoder phase)
  f16* XAehi  = (f16*)(ws + 10109184); // [128][32][64][8]       1048576 fl
  f16* XAelo  = (f16*)(ws + 11157760);
  float* Gi   = ws + 12206336;         // [64][3072][64]         12582912
  f16* WOhi   = (f16*)(ws + 10109184); // [1000][64][64][8]      16384000 fl
  f16* WOlo   = (f16*)(ws + 26493184);
  const size_t WS_NEED = (size_t)42877184 * 4;
  if (ws_size < WS_NEED) return;

  hipMemsetAsync(hA, 0, (size_t)H_ * B_ * sizeof(float), stream);
  hipMemsetAsync(frAhi, 0, (size_t)2 * 65536 * sizeof(f16), stream);   // frAhi+frAlo
  hipMemsetAsync(bestPart, 0, (size_t)64 * 256 * 8, stream);
  hipMemsetAsync(bar, 0, 256 * sizeof(float), stream);
  hipMemsetAsync(XAdhi, 0, (size_t)2 * 32768 * sizeof(f16), stream);   // XAdhi+XAdlo

  // ---- one-time weight packs ----
  k_pack_wf<1024><<<3 * H_, 256, 0, stream>>>(W_hh_enc, WHEhi, WHElo);
  k_pack_wf<1024><<<3 * H_, 256, 0, stream>>>(W_hh_dec, WHDhi, WHDlo);
  k_pack_wf<512><<<3 * H_, 128, 0, stream>>>(W_ih_enc, WIEhi, WIElo);
  k_pack_wf<512><<<3 * H_, 128, 0, stream>>>(W_ih_dec, WIDhi, WIDlo);
  k_pack_xe<<<S_ * B_, 128, 0, stream>>>(x, E, XAehi, XAelo);

  // ---- encoder input gates (one GEMM) ----
  k_gates_mfma<<<64 * 24, 256, 0, stream>>>(XAehi, XAelo, WIEhi, WIElo, b_ih_enc, Gi);

  // ---- persistent encoder (64 steps, 1 launch) ----
  k_enc_persist<<<NBLK, 256, 0, stream>>>(WHEhi, WHElo, Gi, b_hh_enc, hA, preH,
                                          frAhi, frAlo, bar + 0, bar + 32);

  // ---- latent ----
  k_mu_lv_z<<<64, 256, 0, stream>>>(hA, W_mu, b_mu, W_lv, b_lv, eps,
                                    out + OFF_MU, out + OFF_LV, zT);
  k_proj<<<256, 256, 0, stream>>>(zT, W_proj, b_proj, dA, frAhi, frAlo);

  // ---- pack W_out (overwrites XAenc+Gi, both dead) ----
  k_pack_wf<1024><<<V_, 256, 0, stream>>>(W_out, WOhi, WOlo);

  // ---- persistent decoder (64 steps, 1 launch) ----
  k_dec_persist<<<NBLK, 256, 0, stream>>>(
      E, WHDhi, WHDlo, WIDhi, WIDlo, WOhi, WOlo,
      b_ih_dec, b_hh_dec, b_out, out, bestPart, preH, preI,
      dA, frAhi, frAlo, XAdhi, XAdlo, bar + 64, bar + 96);
}